// Round 7
// baseline (881.625 us; speedup 1.0000x reference)
//
#include <hip/hip_runtime.h>

#define NN 50000      // nodes per side
#define NE 800000     // edges per side
#define FIN 64        // input features
#define HH 96         // hidden size
#define NG 256        // graphs per batch
#define NB ((NN + 255) / 256)   // node blocks
#define NPB 196       // nodes per dst-bucket
#define NBKT 256      // buckets (NBKT*NPB = 50176 >= NN)
#define NSUB (NBKT * 8)   // 8 XCD-local sub-buckets per bucket
#define CAP 576       // sub-bucket capacity (mean 391, +9.4 sigma)

// ---------------------------------------------------------------- helpers
__device__ __forceinline__ float wave_sum(float v) {
    #pragma unroll
    for (int off = 32; off > 0; off >>= 1) v += __shfl_down(v, off, 64);
    return v;
}
__device__ __forceinline__ float wave_max(float v) {
    #pragma unroll
    for (int off = 32; off > 0; off >>= 1) v = fmaxf(v, __shfl_down(v, off, 64));
    return v;
}
__device__ __forceinline__ float bf2f(unsigned short b) {
    return __uint_as_float(((unsigned int)b) << 16);
}
__device__ __forceinline__ unsigned short f2bf(float f) {
    unsigned int u = __float_as_uint(f);
    u += 0x7FFFu + ((u >> 16) & 1u);          // round-to-nearest-even
    return (unsigned short)(u >> 16);
}

// ---------------------------------------------------------------- permute pass A:
// scatter packed (src<<8 | localdst) into XCD-local sub-bucket append regions.
__global__ __launch_bounds__(256) void permuteA(const int* __restrict__ srcP,
                                                const int* __restrict__ dstP,
                                                const int* __restrict__ srcD,
                                                const int* __restrict__ dstD,
                                                int* __restrict__ subCur,
                                                unsigned int* __restrict__ tmpP,
                                                unsigned int* __restrict__ tmpD) {
    int e = blockIdx.x * 256 + threadIdx.x;
    if (e >= NE) return;
    int side = blockIdx.y;
    const int* src = side ? srcD : srcP;
    const int* dst = side ? dstD : dstP;
    unsigned int* tmp = side ? tmpD : tmpP;
    int lin = blockIdx.x + blockIdx.y * gridDim.x;
    int xcd = lin & 7;                        // dispatch round-robins XCDs
    int s = src[e], d = dst[e];
    int b = d / NPB;
    int ld = d - b * NPB;
    int slot = atomicAdd(&subCur[side * NSUB + b * 8 + xcd], 1);
    if (slot < CAP)
        tmp[(size_t)(b * 8 + xcd) * CAP + slot] = ((unsigned int)s << 8) | (unsigned int)ld;
}

// ---------------------------------------------------------------- bucket totals -> exclusive base
__global__ __launch_bounds__(256) void bucket_scan(const int* __restrict__ subCur,
                                                   int* __restrict__ bucketBase) {
    int side = blockIdx.x, t = threadIdx.x;
    __shared__ int h[256], s[256];
    int tot = 0;
    #pragma unroll
    for (int x = 0; x < 8; ++x) tot += subCur[side * NSUB + t * 8 + x];
    h[t] = tot; s[t] = tot;
    __syncthreads();
    for (int off = 1; off < 256; off <<= 1) {
        int v = (t >= off) ? s[t - off] : 0;
        __syncthreads();
        s[t] += v;
        __syncthreads();
    }
    bucketBase[side * (NBKT + 1) + t] = s[t] - h[t];
    if (t == 255) bucketBase[side * (NBKT + 1) + 256] = s[255];
}

// ---------------------------------------------------------------- permute pass B:
// per bucket: LDS histogram -> scan -> rowptr/dinv, then dense scatter of eSrc.
__global__ __launch_bounds__(256) void permuteB(const unsigned int* __restrict__ tmpP,
                                                const unsigned int* __restrict__ tmpD,
                                                const int* __restrict__ subCur,
                                                const int* __restrict__ bucketBase,
                                                int* __restrict__ rowptr2,
                                                float* __restrict__ dinv2,
                                                int* __restrict__ eSrcP,
                                                int* __restrict__ eSrcD) {
    int b = blockIdx.x, side = blockIdx.y, t = threadIdx.x;
    const unsigned int* tmp = side ? tmpD : tmpP;
    int* eS = side ? eSrcD : eSrcP;
    __shared__ int h[256], s[256], cur[NPB];
    __shared__ int cnt8[8];
    h[t] = 0;
    if (t < 8) cnt8[t] = subCur[side * NSUB + b * 8 + t];
    __syncthreads();
    int node0 = b * NPB;
    int nn = min(NN - node0, NPB);
    for (int x = 0; x < 8; ++x) {
        int m = min(cnt8[x], CAP);
        const unsigned int* base = tmp + (size_t)(b * 8 + x) * CAP;
        for (int i = t; i < m; i += 256)
            atomicAdd(&h[base[i] & 255], 1);
    }
    __syncthreads();
    s[t] = h[t];
    __syncthreads();
    for (int off = 1; off < 256; off <<= 1) {
        int v = (t >= off) ? s[t - off] : 0;
        __syncthreads();
        s[t] += v;
        __syncthreads();
    }
    int bbase = bucketBase[side * (NBKT + 1) + b];
    int excl = s[t] - h[t];
    if (t < nn) {
        rowptr2[side * (NN + 1) + node0 + t] = bbase + excl;
        cur[t] = bbase + excl;
        dinv2[side * NN + node0 + t] = rsqrtf((float)h[t] + 1.0f);
    }
    if (b == NBKT - 1 && t == 0)
        rowptr2[side * (NN + 1) + NN] = bbase + s[255];
    __syncthreads();
    for (int x = 0; x < 8; ++x) {
        int m = min(cnt8[x], CAP);
        const unsigned int* base = tmp + (size_t)(b * 8 + x) * CAP;
        for (int i = t; i < m; i += 256) {
            unsigned int e = base[i];
            int pos = atomicAdd(&cur[e & 255], 1);
            eS[pos] = (int)(e >> 8);
        }
    }
}

// ---------------------------------------------------------------- graph offsets (batch sorted; init fused)
__global__ __launch_bounds__(256) void start_both(const int* __restrict__ batchP,
                                                  const int* __restrict__ batchD,
                                                  int* __restrict__ start2) {
    int i = blockIdx.x * 256 + threadIdx.x;
    if (i >= NN) return;
    int side = blockIdx.y;
    const int* batch = side ? batchD : batchP;
    int* start = start2 + side * (NG + 1);
    int b = batch[i];
    int prev = (i == 0) ? -1 : batch[i - 1];
    for (int g = prev + 1; g <= b; ++g) start[g] = i;
    if (i == NN - 1) {
        for (int g = b + 1; g <= NG; ++g) start[g] = NN;
    }
}

// ---------------------------------------------------------------- gate MLP (both sides)
__global__ __launch_bounds__(128) void gate_both(const float* __restrict__ xP,
                                                 const float* __restrict__ xD,
                                                 const float* __restrict__ gW1,
                                                 const float* __restrict__ gb1,
                                                 const float* __restrict__ gW2,
                                                 const float* __restrict__ gb2,
                                                 float* __restrict__ gate2) {
    __shared__ float w1[64 * 64];
    __shared__ float xs[128 * 65];
    __shared__ float b1[64], w2[64];
    int side = blockIdx.y;
    const float* x = side ? xD : xP;
    float* gate = gate2 + side * NN;
    int t = threadIdx.x;
    int base = blockIdx.x * 128;
    for (int idx = t; idx < 64 * 64; idx += 128) w1[idx] = gW1[idx];
    if (t < 64) { b1[t] = gb1[t]; w2[t] = gW2[t]; }
    for (int idx = t; idx < 128 * 64; idx += 128) {
        int n = idx >> 6, k = idx & 63;
        int gn = base + n;
        xs[n * 65 + k] = (gn < NN) ? x[(size_t)gn * 64 + k] : 0.0f;
    }
    __syncthreads();

    float hid[64];
    #pragma unroll
    for (int j = 0; j < 64; ++j) hid[j] = b1[j];
    for (int k = 0; k < 64; ++k) {
        float xv = xs[t * 65 + k];
        #pragma unroll
        for (int j = 0; j < 64; ++j) hid[j] += xv * w1[k * 64 + j];
    }
    float acc = gb2[0];
    #pragma unroll
    for (int j = 0; j < 64; ++j) acc += fmaxf(hid[j], 0.0f) * w2[j];
    int n = base + t;
    if (n < NN) gate[n] = acc;
}

// ---------------------------------------------------------------- node GEMM: xw(bf16) = (relu?)in @ W
template <int K, bool RELU>
__global__ __launch_bounds__(256) void gemm_both(const float* __restrict__ inP,
                                                 const float* __restrict__ inD,
                                                 const float* __restrict__ WP,
                                                 const float* __restrict__ WD,
                                                 ushort4* __restrict__ xwP,
                                                 ushort4* __restrict__ xwD) {
    int n = blockIdx.x * 256 + threadIdx.x;
    if (n >= NN) return;
    int side = blockIdx.z;
    const float* x = side ? inD : inP;
    const float* W = side ? WD : WP;
    ushort4* xw = side ? xwD : xwP;
    int c0 = blockIdx.y * 24;
    float xr[K];
    #pragma unroll
    for (int k4 = 0; k4 < K; k4 += 4) {
        float4 v = *reinterpret_cast<const float4*>(x + (size_t)n * K + k4);
        if (RELU) {
            v.x = fmaxf(v.x, 0.0f); v.y = fmaxf(v.y, 0.0f);
            v.z = fmaxf(v.z, 0.0f); v.w = fmaxf(v.w, 0.0f);
        }
        xr[k4] = v.x; xr[k4 + 1] = v.y; xr[k4 + 2] = v.z; xr[k4 + 3] = v.w;
    }
    #pragma unroll
    for (int c = c0; c < c0 + 24; c += 4) {
        float a0 = 0.f, a1 = 0.f, a2 = 0.f, a3 = 0.f;
        #pragma unroll
        for (int k = 0; k < K; ++k) {
            float4 w = *reinterpret_cast<const float4*>(W + k * HH + c);  // uniform
            a0 += xr[k] * w.x; a1 += xr[k] * w.y;
            a2 += xr[k] * w.z; a3 += xr[k] * w.w;
        }
        ushort4 o;
        o.x = f2bf(a0); o.y = f2bf(a1); o.z = f2bf(a2); o.w = f2bf(a3);
        xw[n * 24 + (c >> 2)] = o;
    }
}

// ---------------------------------------------------------------- CSR gather (bf16 xw, norm from dinv)
__global__ __launch_bounds__(256) void gather_both(const ushort4* __restrict__ xwP,
                                                   const ushort4* __restrict__ xwD,
                                                   const float* __restrict__ dinv2,
                                                   const float* __restrict__ biasP,
                                                   const float* __restrict__ biasD,
                                                   const int* __restrict__ rowptr2,
                                                   const int* __restrict__ eSrcP,
                                                   const int* __restrict__ eSrcD,
                                                   float* __restrict__ aggP,
                                                   float* __restrict__ aggD) {
    int i = blockIdx.x * 256 + threadIdx.x;   // over NN*24 4-feature chunks
    if (i >= NN * 24) return;
    int side = blockIdx.y;
    const ushort4* xw = side ? xwD : xwP;
    const float* dv = dinv2 + side * NN;
    const float* bias = side ? biasD : biasP;
    const int* rp = rowptr2 + side * (NN + 1);
    const int* es = side ? eSrcD : eSrcP;
    float* agg = side ? aggD : aggP;

    int n = i / 24, q = i - n * 24;
    int r0 = rp[n], r1 = rp[n + 1];
    float ex = 0.f, ey = 0.f, ez = 0.f, ew = 0.f;
    int r = r0;
    for (; r + 2 <= r1; r += 2) {              // unroll-2: two independent chains
        int s0 = es[r], s1 = es[r + 1];
        float w0 = dv[s0], w1 = dv[s1];
        ushort4 u0 = xw[s0 * 24 + q];
        ushort4 u1 = xw[s1 * 24 + q];
        ex += w0 * bf2f(u0.x) + w1 * bf2f(u1.x);
        ey += w0 * bf2f(u0.y) + w1 * bf2f(u1.y);
        ez += w0 * bf2f(u0.z) + w1 * bf2f(u1.z);
        ew += w0 * bf2f(u0.w) + w1 * bf2f(u1.w);
    }
    if (r < r1) {
        int s0 = es[r];
        float w0 = dv[s0];
        ushort4 u0 = xw[s0 * 24 + q];
        ex += w0 * bf2f(u0.x); ey += w0 * bf2f(u0.y);
        ez += w0 * bf2f(u0.z); ew += w0 * bf2f(u0.w);
    }
    float d = dv[n], d2 = d * d;
    ushort4 su = xw[i];
    float4 b = reinterpret_cast<const float4*>(bias)[q];
    float4 o;
    o.x = d2 * bf2f(su.x) + d * ex + b.x;
    o.y = d2 * bf2f(su.y) + d * ey + b.y;
    o.z = d2 * bf2f(su.z) + d * ez + b.z;
    o.w = d2 * bf2f(su.w) + d * ew + b.w;
    reinterpret_cast<float4*>(agg)[i] = o;
}

// ---------------------------------------------------------------- per-graph max + denom + weights
__global__ __launch_bounds__(256) void pool_ab_wgt(const float* __restrict__ gate2,
                                                   const int* __restrict__ start2,
                                                   float* __restrict__ den2,
                                                   float* __restrict__ wgt2) {
    int side = blockIdx.y, g = blockIdx.x, t = threadIdx.x;
    const float* gate = gate2 + side * NN;
    const int* start = start2 + side * (NG + 1);
    float* den = den2 + side * NG;
    float* wgt = wgt2 + side * NN;
    int s = start[g], e = start[g + 1];
    __shared__ float red[4];
    __shared__ float s_m;

    float lm = -3.0e38f;
    for (int i = s + t; i < e; i += 256) lm = fmaxf(lm, gate[i]);
    lm = wave_max(lm);
    if ((t & 63) == 0) red[t >> 6] = lm;
    __syncthreads();
    if (t == 0) s_m = fmaxf(fmaxf(red[0], red[1]), fmaxf(red[2], red[3]));
    __syncthreads();
    float m = s_m;

    float ls = 0.0f;
    for (int i = s + t; i < e; i += 256) {
        float w = expf(gate[i] - m);
        wgt[i] = w;
        ls += w;
    }
    ls = wave_sum(ls);
    __syncthreads();
    if ((t & 63) == 0) red[t >> 6] = ls;
    __syncthreads();
    if (t == 0) den[g] = red[0] + red[1] + red[2] + red[3];
}

// ---------------------------------------------------------------- node-parallel att pool (raw x)
__global__ __launch_bounds__(256) void pool_att_both(const float* __restrict__ wgt2,
                                                     const float* __restrict__ xP,
                                                     const float* __restrict__ xD,
                                                     const int* __restrict__ batchP,
                                                     const int* __restrict__ batchD,
                                                     float* __restrict__ attP,
                                                     float* __restrict__ attD) {
    int side = blockIdx.y;
    const float* w = wgt2 + side * NN;
    const float* x = side ? xD : xP;
    const int* batch = side ? batchD : batchP;
    float* attRaw = side ? attD : attP;
    int base = blockIdx.x * 64;
    int t = threadIdx.x;
    int f = t & 63, sub = t >> 6;          // 4 node subgroups
    float acc = 0.0f;
    int cur = -1;
    for (int j = 0; j < 16; ++j) {
        int i = base + sub + j * 4;        // monotone in j
        if (i >= NN) break;
        int g = batch[i];
        if (g != cur) {
            if (cur >= 0) atomicAdd(&attRaw[cur * FIN + f], acc);
            cur = g; acc = 0.0f;
        }
        acc += w[i] * x[(size_t)i * FIN + f];
    }
    if (cur >= 0) atomicAdd(&attRaw[cur * FIN + f], acc);
}

// ---------------------------------------------------------------- node-parallel mean pool (h fp32)
__global__ __launch_bounds__(256) void pool_mean_both(const float* __restrict__ hP,
                                                      const float* __restrict__ hD,
                                                      const int* __restrict__ batchP,
                                                      const int* __restrict__ batchD,
                                                      float* __restrict__ meanP,
                                                      float* __restrict__ meanD) {
    int t = threadIdx.x;
    if (t >= 240) return;
    int side = blockIdx.y;
    const float* h = side ? hD : hP;
    const int* batch = side ? batchD : batchP;
    float* meanRaw = side ? meanD : meanP;
    int q = t % 24, sub = t / 24;          // 10 node subgroups
    int base = blockIdx.x * 80;
    float4 acc = {0.f, 0.f, 0.f, 0.f};
    int cur = -1;
    for (int j = 0; j < 8; ++j) {
        int i = base + sub + j * 10;       // monotone in j
        if (i >= NN) continue;
        int g = batch[i];
        if (g != cur) {
            if (cur >= 0) {
                float* o = meanRaw + cur * HH + q * 4;
                atomicAdd(o + 0, acc.x); atomicAdd(o + 1, acc.y);
                atomicAdd(o + 2, acc.z); atomicAdd(o + 3, acc.w);
            }
            cur = g; acc.x = acc.y = acc.z = acc.w = 0.f;
        }
        float4 v = reinterpret_cast<const float4*>(h)[(size_t)i * 24 + q];
        acc.x += v.x; acc.y += v.y; acc.z += v.z; acc.w += v.w;
    }
    if (cur >= 0) {
        float* o = meanRaw + cur * HH + q * 4;
        atomicAdd(o + 0, acc.x); atomicAdd(o + 1, acc.y);
        atomicAdd(o + 2, acc.z); atomicAdd(o + 3, acc.w);
    }
}

// ---------------------------------------------------------------- final MLP (+ pooled normalization)
__global__ __launch_bounds__(128) void final_mlp(const float* __restrict__ meanP,
                                                 const float* __restrict__ meanD,
                                                 const float* __restrict__ attP,
                                                 const float* __restrict__ attD,
                                                 const float* __restrict__ den2,
                                                 const int* __restrict__ start2,
                                                 const float* __restrict__ lW0,
                                                 const float* __restrict__ lb0,
                                                 const float* __restrict__ lW1,
                                                 const float* __restrict__ lb1,
                                                 float* __restrict__ out) {
    __shared__ float in[2 * HH + 2 * FIN];   // 320
    __shared__ float red[2];
    int g = blockIdx.x, t = threadIdx.x;
    const int* startP = start2;
    const int* startD = start2 + (NG + 1);
    float cP = fmaxf((float)(startP[g + 1] - startP[g]), 1.0f);
    float cD = fmaxf((float)(startD[g + 1] - startD[g]), 1.0f);
    float dP = den2[g], dD = den2[NG + g];
    for (int idx = t; idx < 320; idx += 128) {
        float v;
        if (idx < 96)       v = meanP[g * HH + idx] / cP;
        else if (idx < 192) v = meanD[g * HH + idx - 96] / cD;
        else if (idx < 256) v = (dP > 0.f) ? attP[g * FIN + idx - 192] / dP : 0.0f;
        else                v = (dD > 0.f) ? attD[g * FIN + idx - 256] / dD : 0.0f;
        in[idx] = v;
    }
    __syncthreads();
    float hidv = 0.0f;
    if (t < HH) {
        float acc = lb0[t];
        for (int k = 0; k < 320; ++k) acc += in[k] * lW0[k * HH + t];
        hidv = fmaxf(acc, 0.0f) * lW1[t];
    }
    float v = wave_sum(hidv);
    if ((t & 63) == 0) red[t >> 6] = v;
    __syncthreads();
    if (t == 0) out[g] = red[0] + red[1] + lb1[0];
}

// ---------------------------------------------------------------- launch
extern "C" void kernel_launch(void* const* d_in, const int* in_sizes, int n_in,
                              void* d_out, int out_size, void* d_ws, size_t ws_size,
                              hipStream_t stream) {
    const float* x_p = (const float*)d_in[0];
    const float* x_d = (const float*)d_in[1];
    const int* ei_p = (const int*)d_in[4];
    const int* ei_d = (const int*)d_in[5];
    const int* batch_p = (const int*)d_in[6];
    const int* batch_d = (const int*)d_in[7];
    const float* Wp0 = (const float*)d_in[8];  const float* bp0 = (const float*)d_in[9];
    const float* Wp1 = (const float*)d_in[10]; const float* bp1 = (const float*)d_in[11];
    const float* Wp2 = (const float*)d_in[12]; const float* bp2 = (const float*)d_in[13];
    const float* Wd0 = (const float*)d_in[14]; const float* bd0 = (const float*)d_in[15];
    const float* Wd1 = (const float*)d_in[16]; const float* bd1 = (const float*)d_in[17];
    const float* Wd2 = (const float*)d_in[18]; const float* bd2 = (const float*)d_in[19];
    const float* gW1 = (const float*)d_in[20]; const float* gb1 = (const float*)d_in[21];
    const float* gW2 = (const float*)d_in[22]; const float* gb2 = (const float*)d_in[23];
    const float* lW0 = (const float*)d_in[24]; const float* lb0 = (const float*)d_in[25];
    const float* lW1 = (const float*)d_in[26]; const float* lb1 = (const float*)d_in[27];

    const int* src_p = ei_p;        const int* dst_p = ei_p + NE;
    const int* src_d = ei_d;        const int* dst_d = ei_d + NE;

    // -------- workspace carve-up
    char* ws = (char*)d_ws;
    size_t off = 0;
    auto alloc = [&](size_t bytes) -> void* {
        void* p = ws + off;
        off = (off + bytes + 255) & ~(size_t)255;
        return p;
    };
    float* agg_p = (float*)alloc((size_t)NN * HH * 4);        // fp32 layer io
    float* agg_d = (float*)alloc((size_t)NN * HH * 4);
    ushort4* xw_p = (ushort4*)alloc((size_t)NN * HH * 2);     // bf16 gemm out
    ushort4* xw_d = (ushort4*)alloc((size_t)NN * HH * 2);
    float* dinv2 = (float*)alloc((size_t)2 * NN * 4);
    int* rowptr2 = (int*)alloc((size_t)2 * (NN + 1) * 4);
    int* eSrc_p = (int*)alloc((size_t)NE * 4);
    int* eSrc_d = (int*)alloc((size_t)NE * 4);
    float* gate2 = (float*)alloc((size_t)2 * NN * 4);
    float* wgt2 = (float*)alloc((size_t)2 * NN * 4);
    int* start2 = (int*)alloc((size_t)2 * (NG + 1) * 4);
    float* den2 = (float*)alloc((size_t)2 * NG * 4);
    int* bucketBase = (int*)alloc((size_t)2 * (NBKT + 1) * 4);
    int* subCur = (int*)alloc((size_t)2 * NSUB * 4);          // zeroed below
    float* pooled = (float*)alloc((size_t)NG * (2 * HH + 2 * FIN) * 4);
    float* meanP = pooled;
    float* meanD = meanP + (size_t)NG * HH;
    float* attP  = meanD + (size_t)NG * HH;
    float* attD  = attP + (size_t)NG * FIN;
    // tmp edge buckets alias agg_p (disjoint lifetime: permuteA/B finish before gather L0)
    unsigned int* tmp_p = (unsigned int*)agg_p;
    unsigned int* tmp_d = tmp_p + (size_t)NBKT * 8 * CAP;     // 2*4.7MB < 19.2MB agg_p
    (void)ws_size; (void)n_in; (void)in_sizes; (void)out_size;

    const int BE = (NE + 255) / 256;
    const int BNV = (NN * 24 + 255) / 256;
    const dim3 G2E(BE, 2), G2N(NB, 2), G2V(BNV, 2);
    const dim3 GEMM_GRID(NB, 4, 2);
    const dim3 GATE_GRID((NN + 127) / 128, 2);
    const dim3 GAB(NG, 2);
    const dim3 GATT((NN + 63) / 64, 2);
    const dim3 GMEAN((NN + 79) / 80, 2);
    const dim3 GBKT(NBKT, 2);

    // -------- zero subCur + pooled (contiguous region, one memset)
    size_t zlen = (size_t)((char*)(pooled + (size_t)NG * (2 * HH + 2 * FIN)) - (char*)subCur);
    hipMemsetAsync(subCur, 0, zlen, stream);

    // -------- CSR build (2-pass bucketed) + offsets + gate + att pooling
    permuteA<<<G2E, 256, 0, stream>>>(src_p, dst_p, src_d, dst_d, subCur, tmp_p, tmp_d);
    bucket_scan<<<2, 256, 0, stream>>>(subCur, bucketBase);
    permuteB<<<GBKT, 256, 0, stream>>>(tmp_p, tmp_d, subCur, bucketBase,
                                       rowptr2, dinv2, eSrc_p, eSrc_d);
    start_both<<<G2N, 256, 0, stream>>>(batch_p, batch_d, start2);
    gate_both<<<GATE_GRID, 128, 0, stream>>>(x_p, x_d, gW1, gb1, gW2, gb2, gate2);
    pool_ab_wgt<<<GAB, 256, 0, stream>>>(gate2, start2, den2, wgt2);
    pool_att_both<<<GATT, 256, 0, stream>>>(wgt2, x_p, x_d, batch_p, batch_d, attP, attD);

    // -------- 3 GCN layers, both sides per dispatch
    gemm_both<FIN, false><<<GEMM_GRID, 256, 0, stream>>>(x_p, x_d, Wp0, Wd0, xw_p, xw_d);
    gather_both<<<G2V, 256, 0, stream>>>(xw_p, xw_d, dinv2, bp0, bd0, rowptr2, eSrc_p, eSrc_d, agg_p, agg_d);
    gemm_both<HH, true><<<GEMM_GRID, 256, 0, stream>>>(agg_p, agg_d, Wp1, Wd1, xw_p, xw_d);
    gather_both<<<G2V, 256, 0, stream>>>(xw_p, xw_d, dinv2, bp1, bd1, rowptr2, eSrc_p, eSrc_d, agg_p, agg_d);
    gemm_both<HH, true><<<GEMM_GRID, 256, 0, stream>>>(agg_p, agg_d, Wp2, Wd2, xw_p, xw_d);
    gather_both<<<G2V, 256, 0, stream>>>(xw_p, xw_d, dinv2, bp2, bd2, rowptr2, eSrc_p, eSrc_d, agg_p, agg_d);
    pool_mean_both<<<GMEAN, 256, 0, stream>>>(agg_p, agg_d, batch_p, batch_d, meanP, meanD);

    // -------- final MLP
    final_mlp<<<NG, 128, 0, stream>>>(meanP, meanD, attP, attD, den2, start2,
                                      lW0, lb0, lW1, lb1, (float*)d_out);
}

// Round 9
// 686.349 us; speedup vs baseline: 1.2845x; 1.2845x over previous
//
#include <hip/hip_runtime.h>

#define NN 50000      // nodes per side
#define NE 800000     // edges per side
#define FIN 64        // input features
#define HH 96         // hidden size
#define NG 256        // graphs per batch
#define NB ((NN + 255) / 256)   // node blocks
#define NPB 196       // nodes per dst-bucket
#define NCB 256       // coarse buckets (NCB*NPB = 50176 >= NN)
#define BA 256        // pass-A blocks per side
#define EPB (NE / BA) // 3125 edges per pass-A block (exact)
#define CAPA 48       // per-(block,bucket) segment capacity (mean 12.2)
#define CAPB 3584     // per-bucket total capacity (mean 3125, +8.2 sigma)

// ---------------------------------------------------------------- helpers
__device__ __forceinline__ float wave_sum(float v) {
    #pragma unroll
    for (int off = 32; off > 0; off >>= 1) v += __shfl_down(v, off, 64);
    return v;
}
__device__ __forceinline__ float wave_max(float v) {
    #pragma unroll
    for (int off = 32; off > 0; off >>= 1) v = fmaxf(v, __shfl_down(v, off, 64));
    return v;
}
__device__ __forceinline__ float bf2f(unsigned short b) {
    return __uint_as_float(((unsigned int)b) << 16);
}
__device__ __forceinline__ unsigned short f2bf(float f) {
    unsigned int u = __float_as_uint(f);
    u += 0x7FFFu + ((u >> 16) & 1u);          // round-to-nearest-even
    return (unsigned short)(u >> 16);
}

// ---------------------------------------------------------------- permute pass A:
// LDS-binned counting-sort pass: private per-block segments, zero global atomics.
__global__ __launch_bounds__(256) void permuteA(const int* __restrict__ srcP,
                                                const int* __restrict__ dstP,
                                                const int* __restrict__ srcD,
                                                const int* __restrict__ dstD,
                                                unsigned int* __restrict__ tmpP,
                                                unsigned int* __restrict__ tmpD,
                                                int* __restrict__ cntA) {
    __shared__ int cnt[NCB];
    __shared__ unsigned int stage[NCB][CAPA];   // 48 KB
    int t = threadIdx.x, blk = blockIdx.x, side = blockIdx.y;
    const int* src = side ? srcD : srcP;
    const int* dst = side ? dstD : dstP;
    unsigned int* tmp = side ? tmpD : tmpP;
    cnt[t] = 0;
    __syncthreads();
    int e0 = blk * EPB;
    for (int i = t; i < EPB; i += 256) {
        int s = src[e0 + i], d = dst[e0 + i];
        int b = d / NPB;                       // magic-multiply (const)
        int ld = d - b * NPB;                  // < 196, fits 8 bits
        int slot = atomicAdd(&cnt[b], 1);      // LDS atomic, 256 counters
        if (slot < CAPA)
            stage[b][slot] = ((unsigned int)s << 8) | (unsigned int)ld;
    }
    __syncthreads();
    // compact coalesced write-out of all segments
    for (int idx = t; idx < NCB * CAPA; idx += 256) {
        int b = idx / CAPA, j = idx - b * CAPA;
        if (j < cnt[b])
            tmp[((size_t)blk * NCB + b) * CAPA + j] = stage[b][j];
    }
    cntA[(side * BA + blk) * NCB + t] = min(cnt[t], CAPA);
}

// ---------------------------------------------------------------- bucket totals -> exclusive base
__global__ __launch_bounds__(256) void bucket_scan(const int* __restrict__ cntA,
                                                   int* __restrict__ bucketBase) {
    int side = blockIdx.x, t = threadIdx.x;
    __shared__ int sc[NCB];
    __shared__ int tot_s[NCB];
    int tot = 0;
    for (int blk = 0; blk < BA; ++blk)
        tot += cntA[(side * BA + blk) * NCB + t];   // coalesced across t
    tot_s[t] = tot; sc[t] = tot;
    __syncthreads();
    for (int off = 1; off < NCB; off <<= 1) {
        int v = (t >= off) ? sc[t - off] : 0;
        __syncthreads();
        sc[t] += v;
        __syncthreads();
    }
    bucketBase[side * (NCB + 1) + t] = sc[t] - tot_s[t];
    if (t == NCB - 1) bucketBase[side * (NCB + 1) + NCB] = sc[t];
}

// ---------------------------------------------------------------- permute pass B:
// per bucket: histogram -> scan -> rowptr/dinv, scatter src to LDS, coalesced write.
__global__ __launch_bounds__(256) void permuteB(const unsigned int* __restrict__ tmpP,
                                                const unsigned int* __restrict__ tmpD,
                                                const int* __restrict__ cntA,
                                                const int* __restrict__ bucketBase,
                                                int* __restrict__ rowptr2,
                                                float* __restrict__ dinv2,
                                                int* __restrict__ eSrcP,
                                                int* __restrict__ eSrcD) {
    __shared__ int segLen[BA];
    __shared__ int hist[256];
    __shared__ int sc[256];
    __shared__ int cursor[NPB];
    __shared__ int srcStage[CAPB];   // 14 KB
    int b = blockIdx.x, side = blockIdx.y, t = threadIdx.x;
    const unsigned int* tmp = side ? tmpD : tmpP;
    int* eS = side ? eSrcD : eSrcP;
    segLen[t] = cntA[(side * BA + t) * NCB + b];   // t indexes pass-A block
    hist[t] = 0;
    __syncthreads();
    // pass 1: histogram of local dst
    for (int idx = t; idx < BA * CAPA; idx += 256) {
        int blk = idx / CAPA, j = idx - blk * CAPA;
        if (j < segLen[blk])
            atomicAdd(&hist[tmp[((size_t)blk * NCB + b) * CAPA + j] & 255], 1);
    }
    __syncthreads();
    sc[t] = hist[t];
    __syncthreads();
    for (int off = 1; off < 256; off <<= 1) {
        int v = (t >= off) ? sc[t - off] : 0;
        __syncthreads();
        sc[t] += v;
        __syncthreads();
    }
    int excl = sc[t] - hist[t];
    int TB = sc[255];
    int GB = bucketBase[side * (NCB + 1) + b];
    int node0 = b * NPB;
    if (t < NPB && node0 + t < NN) {
        rowptr2[side * (NN + 1) + node0 + t] = GB + excl;
        dinv2[side * NN + node0 + t] = rsqrtf((float)hist[t] + 1.0f);
        cursor[t] = excl;
    }
    if (b == NCB - 1 && t == 0) rowptr2[side * (NN + 1) + NN] = GB + TB;
    __syncthreads();
    // pass 2: scatter src ids into LDS by local position
    for (int idx = t; idx < BA * CAPA; idx += 256) {
        int blk = idx / CAPA, j = idx - blk * CAPA;
        if (j < segLen[blk]) {
            unsigned int r = tmp[((size_t)blk * NCB + b) * CAPA + j];
            int pos = atomicAdd(&cursor[r & 255], 1);
            srcStage[pos] = (int)(r >> 8);
        }
    }
    __syncthreads();
    // coalesced burst write
    for (int i = t; i < TB; i += 256) eS[GB + i] = srcStage[i];
}

// ---------------------------------------------------------------- graph offsets (batch sorted; init fused)
__global__ __launch_bounds__(256) void start_both(const int* __restrict__ batchP,
                                                  const int* __restrict__ batchD,
                                                  int* __restrict__ start2) {
    int i = blockIdx.x * 256 + threadIdx.x;
    if (i >= NN) return;
    int side = blockIdx.y;
    const int* batch = side ? batchD : batchP;
    int* start = start2 + side * (NG + 1);
    int b = batch[i];
    int prev = (i == 0) ? -1 : batch[i - 1];
    for (int g = prev + 1; g <= b; ++g) start[g] = i;
    if (i == NN - 1) {
        for (int g = b + 1; g <= NG; ++g) start[g] = NN;
    }
}

// ---------------------------------------------------------------- gate MLP (both sides)
__global__ __launch_bounds__(128) void gate_both(const float* __restrict__ xP,
                                                 const float* __restrict__ xD,
                                                 const float* __restrict__ gW1,
                                                 const float* __restrict__ gb1,
                                                 const float* __restrict__ gW2,
                                                 const float* __restrict__ gb2,
                                                 float* __restrict__ gate2) {
    __shared__ float w1[64 * 64];
    __shared__ float xs[128 * 65];
    __shared__ float b1[64], w2[64];
    int side = blockIdx.y;
    const float* x = side ? xD : xP;
    float* gate = gate2 + side * NN;
    int t = threadIdx.x;
    int base = blockIdx.x * 128;
    for (int idx = t; idx < 64 * 64; idx += 128) w1[idx] = gW1[idx];
    if (t < 64) { b1[t] = gb1[t]; w2[t] = gW2[t]; }
    for (int idx = t; idx < 128 * 64; idx += 128) {
        int n = idx >> 6, k = idx & 63;
        int gn = base + n;
        xs[n * 65 + k] = (gn < NN) ? x[(size_t)gn * 64 + k] : 0.0f;
    }
    __syncthreads();

    float hid[64];
    #pragma unroll
    for (int j = 0; j < 64; ++j) hid[j] = b1[j];
    for (int k = 0; k < 64; ++k) {
        float xv = xs[t * 65 + k];
        #pragma unroll
        for (int j = 0; j < 64; ++j) hid[j] += xv * w1[k * 64 + j];
    }
    float acc = gb2[0];
    #pragma unroll
    for (int j = 0; j < 64; ++j) acc += fmaxf(hid[j], 0.0f) * w2[j];
    int n = base + t;
    if (n < NN) gate[n] = acc;
}

// ---------------------------------------------------------------- node GEMM: xw(bf16) = (relu?)in @ W
template <int K, bool RELU>
__global__ __launch_bounds__(256) void gemm_both(const float* __restrict__ inP,
                                                 const float* __restrict__ inD,
                                                 const float* __restrict__ WP,
                                                 const float* __restrict__ WD,
                                                 ushort4* __restrict__ xwP,
                                                 ushort4* __restrict__ xwD) {
    int n = blockIdx.x * 256 + threadIdx.x;
    if (n >= NN) return;
    int side = blockIdx.z;
    const float* x = side ? inD : inP;
    const float* W = side ? WD : WP;
    ushort4* xw = side ? xwD : xwP;
    int c0 = blockIdx.y * 24;
    float xr[K];
    #pragma unroll
    for (int k4 = 0; k4 < K; k4 += 4) {
        float4 v = *reinterpret_cast<const float4*>(x + (size_t)n * K + k4);
        if (RELU) {
            v.x = fmaxf(v.x, 0.0f); v.y = fmaxf(v.y, 0.0f);
            v.z = fmaxf(v.z, 0.0f); v.w = fmaxf(v.w, 0.0f);
        }
        xr[k4] = v.x; xr[k4 + 1] = v.y; xr[k4 + 2] = v.z; xr[k4 + 3] = v.w;
    }
    #pragma unroll
    for (int c = c0; c < c0 + 24; c += 4) {
        float a0 = 0.f, a1 = 0.f, a2 = 0.f, a3 = 0.f;
        #pragma unroll
        for (int k = 0; k < K; ++k) {
            float4 w = *reinterpret_cast<const float4*>(W + k * HH + c);  // uniform
            a0 += xr[k] * w.x; a1 += xr[k] * w.y;
            a2 += xr[k] * w.z; a3 += xr[k] * w.w;
        }
        ushort4 o;
        o.x = f2bf(a0); o.y = f2bf(a1); o.z = f2bf(a2); o.w = f2bf(a3);
        xw[n * 24 + (c >> 2)] = o;
    }
}

// ---------------------------------------------------------------- CSR gather (bf16 xw, norm from dinv)
__global__ __launch_bounds__(256) void gather_both(const ushort4* __restrict__ xwP,
                                                   const ushort4* __restrict__ xwD,
                                                   const float* __restrict__ dinv2,
                                                   const float* __restrict__ biasP,
                                                   const float* __restrict__ biasD,
                                                   const int* __restrict__ rowptr2,
                                                   const int* __restrict__ eSrcP,
                                                   const int* __restrict__ eSrcD,
                                                   float* __restrict__ aggP,
                                                   float* __restrict__ aggD) {
    int i = blockIdx.x * 256 + threadIdx.x;   // over NN*24 4-feature chunks
    if (i >= NN * 24) return;
    int side = blockIdx.y;
    const ushort4* xw = side ? xwD : xwP;
    const float* dv = dinv2 + side * NN;
    const float* bias = side ? biasD : biasP;
    const int* rp = rowptr2 + side * (NN + 1);
    const int* es = side ? eSrcD : eSrcP;
    float* agg = side ? aggD : aggP;

    int n = i / 24, q = i - n * 24;
    int r0 = rp[n], r1 = rp[n + 1];
    float ex = 0.f, ey = 0.f, ez = 0.f, ew = 0.f;
    int r = r0;
    for (; r + 2 <= r1; r += 2) {              // unroll-2: two independent chains
        int s0 = es[r], s1 = es[r + 1];
        float w0 = dv[s0], w1 = dv[s1];
        ushort4 u0 = xw[s0 * 24 + q];
        ushort4 u1 = xw[s1 * 24 + q];
        ex += w0 * bf2f(u0.x) + w1 * bf2f(u1.x);
        ey += w0 * bf2f(u0.y) + w1 * bf2f(u1.y);
        ez += w0 * bf2f(u0.z) + w1 * bf2f(u1.z);
        ew += w0 * bf2f(u0.w) + w1 * bf2f(u1.w);
    }
    if (r < r1) {
        int s0 = es[r];
        float w0 = dv[s0];
        ushort4 u0 = xw[s0 * 24 + q];
        ex += w0 * bf2f(u0.x); ey += w0 * bf2f(u0.y);
        ez += w0 * bf2f(u0.z); ew += w0 * bf2f(u0.w);
    }
    float d = dv[n], d2 = d * d;
    ushort4 su = xw[i];
    float4 b = reinterpret_cast<const float4*>(bias)[q];
    float4 o;
    o.x = d2 * bf2f(su.x) + d * ex + b.x;
    o.y = d2 * bf2f(su.y) + d * ey + b.y;
    o.z = d2 * bf2f(su.z) + d * ez + b.z;
    o.w = d2 * bf2f(su.w) + d * ew + b.w;
    reinterpret_cast<float4*>(agg)[i] = o;
}

// ---------------------------------------------------------------- per-graph max + denom + weights
__global__ __launch_bounds__(256) void pool_ab_wgt(const float* __restrict__ gate2,
                                                   const int* __restrict__ start2,
                                                   float* __restrict__ den2,
                                                   float* __restrict__ wgt2) {
    int side = blockIdx.y, g = blockIdx.x, t = threadIdx.x;
    const float* gate = gate2 + side * NN;
    const int* start = start2 + side * (NG + 1);
    float* den = den2 + side * NG;
    float* wgt = wgt2 + side * NN;
    int s = start[g], e = start[g + 1];
    __shared__ float red[4];
    __shared__ float s_m;

    float lm = -3.0e38f;
    for (int i = s + t; i < e; i += 256) lm = fmaxf(lm, gate[i]);
    lm = wave_max(lm);
    if ((t & 63) == 0) red[t >> 6] = lm;
    __syncthreads();
    if (t == 0) s_m = fmaxf(fmaxf(red[0], red[1]), fmaxf(red[2], red[3]));
    __syncthreads();
    float m = s_m;

    float ls = 0.0f;
    for (int i = s + t; i < e; i += 256) {
        float w = expf(gate[i] - m);
        wgt[i] = w;
        ls += w;
    }
    ls = wave_sum(ls);
    __syncthreads();
    if ((t & 63) == 0) red[t >> 6] = ls;
    __syncthreads();
    if (t == 0) den[g] = red[0] + red[1] + red[2] + red[3];
}

// ---------------------------------------------------------------- node-parallel att pool (raw x)
__global__ __launch_bounds__(256) void pool_att_both(const float* __restrict__ wgt2,
                                                     const float* __restrict__ xP,
                                                     const float* __restrict__ xD,
                                                     const int* __restrict__ batchP,
                                                     const int* __restrict__ batchD,
                                                     float* __restrict__ attP,
                                                     float* __restrict__ attD) {
    int side = blockIdx.y;
    const float* w = wgt2 + side * NN;
    const float* x = side ? xD : xP;
    const int* batch = side ? batchD : batchP;
    float* attRaw = side ? attD : attP;
    int base = blockIdx.x * 64;
    int t = threadIdx.x;
    int f = t & 63, sub = t >> 6;          // 4 node subgroups
    float acc = 0.0f;
    int cur = -1;
    for (int j = 0; j < 16; ++j) {
        int i = base + sub + j * 4;        // monotone in j
        if (i >= NN) break;
        int g = batch[i];
        if (g != cur) {
            if (cur >= 0) atomicAdd(&attRaw[cur * FIN + f], acc);
            cur = g; acc = 0.0f;
        }
        acc += w[i] * x[(size_t)i * FIN + f];
    }
    if (cur >= 0) atomicAdd(&attRaw[cur * FIN + f], acc);
}

// ---------------------------------------------------------------- node-parallel mean pool (h fp32)
__global__ __launch_bounds__(256) void pool_mean_both(const float* __restrict__ hP,
                                                      const float* __restrict__ hD,
                                                      const int* __restrict__ batchP,
                                                      const int* __restrict__ batchD,
                                                      float* __restrict__ meanP,
                                                      float* __restrict__ meanD) {
    int t = threadIdx.x;
    if (t >= 240) return;
    int side = blockIdx.y;
    const float* h = side ? hD : hP;
    const int* batch = side ? batchD : batchP;
    float* meanRaw = side ? meanD : meanP;
    int q = t % 24, sub = t / 24;          // 10 node subgroups
    int base = blockIdx.x * 80;
    float4 acc = {0.f, 0.f, 0.f, 0.f};
    int cur = -1;
    for (int j = 0; j < 8; ++j) {
        int i = base + sub + j * 10;       // monotone in j
        if (i >= NN) continue;
        int g = batch[i];
        if (g != cur) {
            if (cur >= 0) {
                float* o = meanRaw + cur * HH + q * 4;
                atomicAdd(o + 0, acc.x); atomicAdd(o + 1, acc.y);
                atomicAdd(o + 2, acc.z); atomicAdd(o + 3, acc.w);
            }
            cur = g; acc.x = acc.y = acc.z = acc.w = 0.f;
        }
        float4 v = reinterpret_cast<const float4*>(h)[(size_t)i * 24 + q];
        acc.x += v.x; acc.y += v.y; acc.z += v.z; acc.w += v.w;
    }
    if (cur >= 0) {
        float* o = meanRaw + cur * HH + q * 4;
        atomicAdd(o + 0, acc.x); atomicAdd(o + 1, acc.y);
        atomicAdd(o + 2, acc.z); atomicAdd(o + 3, acc.w);
    }
}

// ---------------------------------------------------------------- final MLP (+ pooled normalization)
__global__ __launch_bounds__(128) void final_mlp(const float* __restrict__ meanP,
                                                 const float* __restrict__ meanD,
                                                 const float* __restrict__ attP,
                                                 const float* __restrict__ attD,
                                                 const float* __restrict__ den2,
                                                 const int* __restrict__ start2,
                                                 const float* __restrict__ lW0,
                                                 const float* __restrict__ lb0,
                                                 const float* __restrict__ lW1,
                                                 const float* __restrict__ lb1,
                                                 float* __restrict__ out) {
    __shared__ float in[2 * HH + 2 * FIN];   // 320
    __shared__ float red[2];
    int g = blockIdx.x, t = threadIdx.x;
    const int* startP = start2;
    const int* startD = start2 + (NG + 1);
    float cP = fmaxf((float)(startP[g + 1] - startP[g]), 1.0f);
    float cD = fmaxf((float)(startD[g + 1] - startD[g]), 1.0f);
    float dP = den2[g], dD = den2[NG + g];
    for (int idx = t; idx < 320; idx += 128) {
        float v;
        if (idx < 96)       v = meanP[g * HH + idx] / cP;
        else if (idx < 192) v = meanD[g * HH + idx - 96] / cD;
        else if (idx < 256) v = (dP > 0.f) ? attP[g * FIN + idx - 192] / dP : 0.0f;
        else                v = (dD > 0.f) ? attD[g * FIN + idx - 256] / dD : 0.0f;
        in[idx] = v;
    }
    __syncthreads();
    float hidv = 0.0f;
    if (t < HH) {
        float acc = lb0[t];
        for (int k = 0; k < 320; ++k) acc += in[k] * lW0[k * HH + t];
        hidv = fmaxf(acc, 0.0f) * lW1[t];
    }
    float v = wave_sum(hidv);
    if ((t & 63) == 0) red[t >> 6] = v;
    __syncthreads();
    if (t == 0) out[g] = red[0] + red[1] + lb1[0];
}

// ---------------------------------------------------------------- launch
extern "C" void kernel_launch(void* const* d_in, const int* in_sizes, int n_in,
                              void* d_out, int out_size, void* d_ws, size_t ws_size,
                              hipStream_t stream) {
    const float* x_p = (const float*)d_in[0];
    const float* x_d = (const float*)d_in[1];
    const int* ei_p = (const int*)d_in[4];
    const int* ei_d = (const int*)d_in[5];
    const int* batch_p = (const int*)d_in[6];
    const int* batch_d = (const int*)d_in[7];
    const float* Wp0 = (const float*)d_in[8];  const float* bp0 = (const float*)d_in[9];
    const float* Wp1 = (const float*)d_in[10]; const float* bp1 = (const float*)d_in[11];
    const float* Wp2 = (const float*)d_in[12]; const float* bp2 = (const float*)d_in[13];
    const float* Wd0 = (const float*)d_in[14]; const float* bd0 = (const float*)d_in[15];
    const float* Wd1 = (const float*)d_in[16]; const float* bd1 = (const float*)d_in[17];
    const float* Wd2 = (const float*)d_in[18]; const float* bd2 = (const float*)d_in[19];
    const float* gW1 = (const float*)d_in[20]; const float* gb1 = (const float*)d_in[21];
    const float* gW2 = (const float*)d_in[22]; const float* gb2 = (const float*)d_in[23];
    const float* lW0 = (const float*)d_in[24]; const float* lb0 = (const float*)d_in[25];
    const float* lW1 = (const float*)d_in[26]; const float* lb1 = (const float*)d_in[27];

    const int* src_p = ei_p;        const int* dst_p = ei_p + NE;
    const int* src_d = ei_d;        const int* dst_d = ei_d + NE;

    // -------- workspace carve-up
    char* ws = (char*)d_ws;
    size_t off = 0;
    auto alloc = [&](size_t bytes) -> void* {
        void* p = ws + off;
        off = (off + bytes + 255) & ~(size_t)255;
        return p;
    };
    float* agg_p = (float*)alloc((size_t)NN * HH * 4);        // fp32 layer io
    float* agg_d = (float*)alloc((size_t)NN * HH * 4);
    ushort4* xw_p = (ushort4*)alloc((size_t)NN * HH * 2);     // bf16 gemm out
    ushort4* xw_d = (ushort4*)alloc((size_t)NN * HH * 2);
    float* dinv2 = (float*)alloc((size_t)2 * NN * 4);
    int* rowptr2 = (int*)alloc((size_t)2 * (NN + 1) * 4);
    int* eSrc_p = (int*)alloc((size_t)NE * 4);
    int* eSrc_d = (int*)alloc((size_t)NE * 4);
    float* gate2 = (float*)alloc((size_t)2 * NN * 4);
    float* wgt2 = (float*)alloc((size_t)2 * NN * 4);
    int* start2 = (int*)alloc((size_t)2 * (NG + 1) * 4);
    float* den2 = (float*)alloc((size_t)2 * NG * 4);
    int* cntA = (int*)alloc((size_t)2 * BA * NCB * 4);        // fully written by permuteA
    int* bucketBase = (int*)alloc((size_t)2 * (NCB + 1) * 4);
    float* pooled = (float*)alloc((size_t)NG * (2 * HH + 2 * FIN) * 4);
    float* meanP = pooled;
    float* meanD = meanP + (size_t)NG * HH;
    float* attP  = meanD + (size_t)NG * HH;
    float* attD  = attP + (size_t)NG * FIN;
    // tmp edge buckets alias agg_p/agg_d (disjoint lifetime: done before gather L0)
    unsigned int* tmp_p = (unsigned int*)agg_p;               // 12.6 MB < 19.2 MB
    unsigned int* tmp_d = (unsigned int*)agg_d;
    (void)ws_size; (void)n_in; (void)in_sizes; (void)out_size;

    const int BNV = (NN * 24 + 255) / 256;
    const dim3 G2N(NB, 2), G2V(BNV, 2);
    const dim3 GEMM_GRID(NB, 4, 2);
    const dim3 GATE_GRID((NN + 127) / 128, 2);
    const dim3 GAB(NG, 2);
    const dim3 GATT((NN + 63) / 64, 2);
    const dim3 GMEAN((NN + 79) / 80, 2);

    // -------- zero pooled accumulators only
    hipMemsetAsync(pooled, 0, (size_t)NG * (2 * HH + 2 * FIN) * 4, stream);

    // -------- CSR build (LDS counting sort) + offsets + gate + att pooling
    permuteA<<<dim3(BA, 2), 256, 0, stream>>>(src_p, dst_p, src_d, dst_d, tmp_p, tmp_d, cntA);
    bucket_scan<<<2, 256, 0, stream>>>(cntA, bucketBase);
    permuteB<<<dim3(NCB, 2), 256, 0, stream>>>(tmp_p, tmp_d, cntA, bucketBase,
                                               rowptr2, dinv2, eSrc_p, eSrc_d);
    start_both<<<G2N, 256, 0, stream>>>(batch_p, batch_d, start2);
    gate_both<<<GATE_GRID, 128, 0, stream>>>(x_p, x_d, gW1, gb1, gW2, gb2, gate2);
    pool_ab_wgt<<<GAB, 256, 0, stream>>>(gate2, start2, den2, wgt2);
    pool_att_both<<<GATT, 256, 0, stream>>>(wgt2, x_p, x_d, batch_p, batch_d, attP, attD);

    // -------- 3 GCN layers, both sides per dispatch
    gemm_both<FIN, false><<<GEMM_GRID, 256, 0, stream>>>(x_p, x_d, Wp0, Wd0, xw_p, xw_d);
    gather_both<<<G2V, 256, 0, stream>>>(xw_p, xw_d, dinv2, bp0, bd0, rowptr2, eSrc_p, eSrc_d, agg_p, agg_d);
    gemm_both<HH, true><<<GEMM_GRID, 256, 0, stream>>>(agg_p, agg_d, Wp1, Wd1, xw_p, xw_d);
    gather_both<<<G2V, 256, 0, stream>>>(xw_p, xw_d, dinv2, bp1, bd1, rowptr2, eSrc_p, eSrc_d, agg_p, agg_d);
    gemm_both<HH, true><<<GEMM_GRID, 256, 0, stream>>>(agg_p, agg_d, Wp2, Wd2, xw_p, xw_d);
    gather_both<<<G2V, 256, 0, stream>>>(xw_p, xw_d, dinv2, bp2, bd2, rowptr2, eSrc_p, eSrc_d, agg_p, agg_d);
    pool_mean_both<<<GMEAN, 256, 0, stream>>>(agg_p, agg_d, batch_p, batch_d, meanP, meanD);

    // -------- final MLP
    final_mlp<<<NG, 128, 0, stream>>>(meanP, meanD, attP, attD, den2, start2,
                                      lW0, lb0, lW1, lb1, (float*)d_out);
}

// Round 10
// 626.905 us; speedup vs baseline: 1.4063x; 1.0948x over previous
//
#include <hip/hip_runtime.h>

#define NN 50000      // nodes per side
#define NE 800000     // edges per side
#define FIN 64        // input features
#define HH 96         // hidden size
#define NG 256        // graphs per batch
#define NB ((NN + 255) / 256)   // node blocks
#define NPB 196       // nodes per dst-bucket
#define NCB 256       // coarse buckets (NCB*NPB = 50176 >= NN)
#define BA 256        // pass-A blocks per side
#define EPB (NE / BA) // 3125 edges per pass-A block (exact)
#define CAPA 48       // per-(block,bucket) segment capacity (mean 12.2)
#define CAPB 3584     // per-bucket total capacity (mean 3125, +8.2 sigma)

// ---------------------------------------------------------------- helpers
__device__ __forceinline__ float wave_sum(float v) {
    #pragma unroll
    for (int off = 32; off > 0; off >>= 1) v += __shfl_down(v, off, 64);
    return v;
}
__device__ __forceinline__ float wave_max(float v) {
    #pragma unroll
    for (int off = 32; off > 0; off >>= 1) v = fmaxf(v, __shfl_down(v, off, 64));
    return v;
}
__device__ __forceinline__ float bf2f(unsigned short b) {
    return __uint_as_float(((unsigned int)b) << 16);
}
__device__ __forceinline__ unsigned short f2bf(float f) {
    unsigned int u = __float_as_uint(f);
    u += 0x7FFFu + ((u >> 16) & 1u);          // round-to-nearest-even
    return (unsigned short)(u >> 16);
}

// ---------------------------------------------------------------- permute pass A:
// LDS-binned counting-sort pass: private per-block segments, zero global atomics.
__global__ __launch_bounds__(256) void permuteA(const int* __restrict__ srcP,
                                                const int* __restrict__ dstP,
                                                const int* __restrict__ srcD,
                                                const int* __restrict__ dstD,
                                                unsigned int* __restrict__ tmpP,
                                                unsigned int* __restrict__ tmpD,
                                                int* __restrict__ cntA) {
    __shared__ int cnt[NCB];
    __shared__ unsigned int stage[NCB][CAPA];   // 48 KB
    int t = threadIdx.x, blk = blockIdx.x, side = blockIdx.y;
    const int* src = side ? srcD : srcP;
    const int* dst = side ? dstD : dstP;
    unsigned int* tmp = side ? tmpD : tmpP;
    cnt[t] = 0;
    __syncthreads();
    int e0 = blk * EPB;
    for (int i = t; i < EPB; i += 256) {
        int s = src[e0 + i], d = dst[e0 + i];
        int b = d / NPB;                       // magic-multiply (const)
        int ld = d - b * NPB;                  // < 196, fits 8 bits
        int slot = atomicAdd(&cnt[b], 1);      // LDS atomic, 256 counters
        if (slot < CAPA)
            stage[b][slot] = ((unsigned int)s << 8) | (unsigned int)ld;
    }
    __syncthreads();
    // compact coalesced write-out of all segments
    for (int idx = t; idx < NCB * CAPA; idx += 256) {
        int b = idx / CAPA, j = idx - b * CAPA;
        if (j < cnt[b])
            tmp[((size_t)blk * NCB + b) * CAPA + j] = stage[b][j];
    }
    cntA[(side * BA + blk) * NCB + t] = min(cnt[t], CAPA);
}

// ---------------------------------------------------------------- bucket totals -> exclusive base
__global__ __launch_bounds__(256) void bucket_scan(const int* __restrict__ cntA,
                                                   int* __restrict__ bucketBase) {
    int side = blockIdx.x, t = threadIdx.x;
    __shared__ int sc[NCB];
    __shared__ int tot_s[NCB];
    int tot = 0;
    for (int blk = 0; blk < BA; ++blk)
        tot += cntA[(side * BA + blk) * NCB + t];   // coalesced across t
    tot_s[t] = tot; sc[t] = tot;
    __syncthreads();
    for (int off = 1; off < NCB; off <<= 1) {
        int v = (t >= off) ? sc[t - off] : 0;
        __syncthreads();
        sc[t] += v;
        __syncthreads();
    }
    bucketBase[side * (NCB + 1) + t] = sc[t] - tot_s[t];
    if (t == NCB - 1) bucketBase[side * (NCB + 1) + NCB] = sc[t];
}

// ---------------------------------------------------------------- permute pass B:
// per bucket: histogram -> scan -> rowptr/dinv, scatter src to LDS, coalesced write.
__global__ __launch_bounds__(256) void permuteB(const unsigned int* __restrict__ tmpP,
                                                const unsigned int* __restrict__ tmpD,
                                                const int* __restrict__ cntA,
                                                const int* __restrict__ bucketBase,
                                                int* __restrict__ rowptr2,
                                                float* __restrict__ dinv2,
                                                int* __restrict__ eSrcP,
                                                int* __restrict__ eSrcD) {
    __shared__ int segLen[BA];
    __shared__ int hist[256];
    __shared__ int sc[256];
    __shared__ int cursor[NPB];
    __shared__ int srcStage[CAPB];   // 14 KB
    int b = blockIdx.x, side = blockIdx.y, t = threadIdx.x;
    const unsigned int* tmp = side ? tmpD : tmpP;
    int* eS = side ? eSrcD : eSrcP;
    segLen[t] = cntA[(side * BA + t) * NCB + b];   // t indexes pass-A block
    hist[t] = 0;
    __syncthreads();
    // pass 1: histogram of local dst
    for (int idx = t; idx < BA * CAPA; idx += 256) {
        int blk = idx / CAPA, j = idx - blk * CAPA;
        if (j < segLen[blk])
            atomicAdd(&hist[tmp[((size_t)blk * NCB + b) * CAPA + j] & 255], 1);
    }
    __syncthreads();
    sc[t] = hist[t];
    __syncthreads();
    for (int off = 1; off < 256; off <<= 1) {
        int v = (t >= off) ? sc[t - off] : 0;
        __syncthreads();
        sc[t] += v;
        __syncthreads();
    }
    int excl = sc[t] - hist[t];
    int TB = sc[255];
    int GB = bucketBase[side * (NCB + 1) + b];
    int node0 = b * NPB;
    if (t < NPB && node0 + t < NN) {
        rowptr2[side * (NN + 1) + node0 + t] = GB + excl;
        dinv2[side * NN + node0 + t] = rsqrtf((float)hist[t] + 1.0f);
        cursor[t] = excl;
    }
    if (b == NCB - 1 && t == 0) rowptr2[side * (NN + 1) + NN] = GB + TB;
    __syncthreads();
    // pass 2: scatter src ids into LDS by local position
    for (int idx = t; idx < BA * CAPA; idx += 256) {
        int blk = idx / CAPA, j = idx - blk * CAPA;
        if (j < segLen[blk]) {
            unsigned int r = tmp[((size_t)blk * NCB + b) * CAPA + j];
            int pos = atomicAdd(&cursor[r & 255], 1);
            srcStage[pos] = (int)(r >> 8);
        }
    }
    __syncthreads();
    // coalesced burst write
    for (int i = t; i < TB; i += 256) eS[GB + i] = srcStage[i];
}

// ---------------------------------------------------------------- graph offsets (batch sorted; init fused)
__global__ __launch_bounds__(256) void start_both(const int* __restrict__ batchP,
                                                  const int* __restrict__ batchD,
                                                  int* __restrict__ start2) {
    int i = blockIdx.x * 256 + threadIdx.x;
    if (i >= NN) return;
    int side = blockIdx.y;
    const int* batch = side ? batchD : batchP;
    int* start = start2 + side * (NG + 1);
    int b = batch[i];
    int prev = (i == 0) ? -1 : batch[i - 1];
    for (int g = prev + 1; g <= b; ++g) start[g] = i;
    if (i == NN - 1) {
        for (int g = b + 1; g <= NG; ++g) start[g] = NN;
    }
}

// ---------------------------------------------------------------- gate MLP v2: occupancy-oriented
// 256 threads = 64 nodes x 4 hidden-quarters; w1 in LDS (16 KB), x row in VGPRs.
__global__ __launch_bounds__(256) void gate_both(const float* __restrict__ xP,
                                                 const float* __restrict__ xD,
                                                 const float* __restrict__ gW1,
                                                 const float* __restrict__ gb1,
                                                 const float* __restrict__ gW2,
                                                 const float* __restrict__ gb2,
                                                 float* __restrict__ gate2) {
    __shared__ float w1[64 * 64];     // 16 KB
    __shared__ float b1v[64], w2v[64];
    __shared__ float partial[256];    // 1 KB
    int side = blockIdx.y;
    const float* x = side ? xD : xP;
    float* gate = gate2 + side * NN;
    int t = threadIdx.x;
    int node = blockIdx.x * 64 + (t & 63);
    int q = t >> 6;                   // quarter: whole wave shares q -> w1 reads broadcast
    for (int idx = t; idx < 64 * 64; idx += 256) w1[idx] = gW1[idx];
    if (t < 64) { b1v[t] = gb1[t]; w2v[t] = gW2[t]; }
    __syncthreads();

    float xr[64];
    if (node < NN) {
        #pragma unroll
        for (int k4 = 0; k4 < 64; k4 += 4) {
            float4 v = *reinterpret_cast<const float4*>(x + (size_t)node * 64 + k4);
            xr[k4] = v.x; xr[k4 + 1] = v.y; xr[k4 + 2] = v.z; xr[k4 + 3] = v.w;
        }
    } else {
        #pragma unroll
        for (int k = 0; k < 64; ++k) xr[k] = 0.0f;
    }
    float hid[16];
    #pragma unroll
    for (int j = 0; j < 16; ++j) hid[j] = b1v[q * 16 + j];
    for (int k = 0; k < 64; ++k) {
        float xv = xr[k];
        #pragma unroll
        for (int j = 0; j < 16; ++j) hid[j] += xv * w1[k * 64 + q * 16 + j];
    }
    float acc = 0.0f;
    #pragma unroll
    for (int j = 0; j < 16; ++j) acc += fmaxf(hid[j], 0.0f) * w2v[q * 16 + j];
    partial[t] = acc;
    __syncthreads();
    if (t < 64 && node < NN)
        gate[node] = partial[t] + partial[64 + t] + partial[128 + t] + partial[192 + t] + gb2[0];
}

// ---------------------------------------------------------------- node GEMM: xw(bf16) = (relu?)in @ W
template <int K, bool RELU>
__global__ __launch_bounds__(256) void gemm_both(const float* __restrict__ inP,
                                                 const float* __restrict__ inD,
                                                 const float* __restrict__ WP,
                                                 const float* __restrict__ WD,
                                                 ushort4* __restrict__ xwP,
                                                 ushort4* __restrict__ xwD) {
    int n = blockIdx.x * 256 + threadIdx.x;
    if (n >= NN) return;
    int side = blockIdx.z;
    const float* x = side ? inD : inP;
    const float* W = side ? WD : WP;
    ushort4* xw = side ? xwD : xwP;
    int c0 = blockIdx.y * 24;
    float xr[K];
    #pragma unroll
    for (int k4 = 0; k4 < K; k4 += 4) {
        float4 v = *reinterpret_cast<const float4*>(x + (size_t)n * K + k4);
        if (RELU) {
            v.x = fmaxf(v.x, 0.0f); v.y = fmaxf(v.y, 0.0f);
            v.z = fmaxf(v.z, 0.0f); v.w = fmaxf(v.w, 0.0f);
        }
        xr[k4] = v.x; xr[k4 + 1] = v.y; xr[k4 + 2] = v.z; xr[k4 + 3] = v.w;
    }
    #pragma unroll
    for (int c = c0; c < c0 + 24; c += 4) {
        float a0 = 0.f, a1 = 0.f, a2 = 0.f, a3 = 0.f;
        #pragma unroll
        for (int k = 0; k < K; ++k) {
            float4 w = *reinterpret_cast<const float4*>(W + k * HH + c);  // uniform
            a0 += xr[k] * w.x; a1 += xr[k] * w.y;
            a2 += xr[k] * w.z; a3 += xr[k] * w.w;
        }
        ushort4 o;
        o.x = f2bf(a0); o.y = f2bf(a1); o.z = f2bf(a2); o.w = f2bf(a3);
        xw[n * 24 + (c >> 2)] = o;
    }
}

// ---------------------------------------------------------------- CSR gather (bf16 xw, norm from dinv)
__global__ __launch_bounds__(256) void gather_both(const ushort4* __restrict__ xwP,
                                                   const ushort4* __restrict__ xwD,
                                                   const float* __restrict__ dinv2,
                                                   const float* __restrict__ biasP,
                                                   const float* __restrict__ biasD,
                                                   const int* __restrict__ rowptr2,
                                                   const int* __restrict__ eSrcP,
                                                   const int* __restrict__ eSrcD,
                                                   float* __restrict__ aggP,
                                                   float* __restrict__ aggD) {
    int i = blockIdx.x * 256 + threadIdx.x;   // over NN*24 4-feature chunks
    if (i >= NN * 24) return;
    int side = blockIdx.y;
    const ushort4* xw = side ? xwD : xwP;
    const float* dv = dinv2 + side * NN;
    const float* bias = side ? biasD : biasP;
    const int* rp = rowptr2 + side * (NN + 1);
    const int* es = side ? eSrcD : eSrcP;
    float* agg = side ? aggD : aggP;

    int n = i / 24, q = i - n * 24;
    int r0 = rp[n], r1 = rp[n + 1];
    float ex = 0.f, ey = 0.f, ez = 0.f, ew = 0.f;
    int r = r0;
    for (; r + 2 <= r1; r += 2) {              // unroll-2: two independent chains
        int s0 = es[r], s1 = es[r + 1];
        float w0 = dv[s0], w1 = dv[s1];
        ushort4 u0 = xw[s0 * 24 + q];
        ushort4 u1 = xw[s1 * 24 + q];
        ex += w0 * bf2f(u0.x) + w1 * bf2f(u1.x);
        ey += w0 * bf2f(u0.y) + w1 * bf2f(u1.y);
        ez += w0 * bf2f(u0.z) + w1 * bf2f(u1.z);
        ew += w0 * bf2f(u0.w) + w1 * bf2f(u1.w);
    }
    if (r < r1) {
        int s0 = es[r];
        float w0 = dv[s0];
        ushort4 u0 = xw[s0 * 24 + q];
        ex += w0 * bf2f(u0.x); ey += w0 * bf2f(u0.y);
        ez += w0 * bf2f(u0.z); ew += w0 * bf2f(u0.w);
    }
    float d = dv[n], d2 = d * d;
    ushort4 su = xw[i];
    float4 b = reinterpret_cast<const float4*>(bias)[q];
    float4 o;
    o.x = d2 * bf2f(su.x) + d * ex + b.x;
    o.y = d2 * bf2f(su.y) + d * ey + b.y;
    o.z = d2 * bf2f(su.z) + d * ez + b.z;
    o.w = d2 * bf2f(su.w) + d * ew + b.w;
    reinterpret_cast<float4*>(agg)[i] = o;
}

// ---------------------------------------------------------------- per-graph max + denom + weights
__global__ __launch_bounds__(256) void pool_ab_wgt(const float* __restrict__ gate2,
                                                   const int* __restrict__ start2,
                                                   float* __restrict__ den2,
                                                   float* __restrict__ wgt2) {
    int side = blockIdx.y, g = blockIdx.x, t = threadIdx.x;
    const float* gate = gate2 + side * NN;
    const int* start = start2 + side * (NG + 1);
    float* den = den2 + side * NG;
    float* wgt = wgt2 + side * NN;
    int s = start[g], e = start[g + 1];
    __shared__ float red[4];
    __shared__ float s_m;

    float lm = -3.0e38f;
    for (int i = s + t; i < e; i += 256) lm = fmaxf(lm, gate[i]);
    lm = wave_max(lm);
    if ((t & 63) == 0) red[t >> 6] = lm;
    __syncthreads();
    if (t == 0) s_m = fmaxf(fmaxf(red[0], red[1]), fmaxf(red[2], red[3]));
    __syncthreads();
    float m = s_m;

    float ls = 0.0f;
    for (int i = s + t; i < e; i += 256) {
        float w = expf(gate[i] - m);
        wgt[i] = w;
        ls += w;
    }
    ls = wave_sum(ls);
    __syncthreads();
    if ((t & 63) == 0) red[t >> 6] = ls;
    __syncthreads();
    if (t == 0) den[g] = red[0] + red[1] + red[2] + red[3];
}

// ---------------------------------------------------------------- node-parallel att pool (raw x)
__global__ __launch_bounds__(256) void pool_att_both(const float* __restrict__ wgt2,
                                                     const float* __restrict__ xP,
                                                     const float* __restrict__ xD,
                                                     const int* __restrict__ batchP,
                                                     const int* __restrict__ batchD,
                                                     float* __restrict__ attP,
                                                     float* __restrict__ attD) {
    int side = blockIdx.y;
    const float* w = wgt2 + side * NN;
    const float* x = side ? xD : xP;
    const int* batch = side ? batchD : batchP;
    float* attRaw = side ? attD : attP;
    int base = blockIdx.x * 64;
    int t = threadIdx.x;
    int f = t & 63, sub = t >> 6;          // 4 node subgroups
    float acc = 0.0f;
    int cur = -1;
    for (int j = 0; j < 16; ++j) {
        int i = base + sub + j * 4;        // monotone in j
        if (i >= NN) break;
        int g = batch[i];
        if (g != cur) {
            if (cur >= 0) atomicAdd(&attRaw[cur * FIN + f], acc);
            cur = g; acc = 0.0f;
        }
        acc += w[i] * x[(size_t)i * FIN + f];
    }
    if (cur >= 0) atomicAdd(&attRaw[cur * FIN + f], acc);
}

// ---------------------------------------------------------------- node-parallel mean pool (h fp32)
__global__ __launch_bounds__(256) void pool_mean_both(const float* __restrict__ hP,
                                                      const float* __restrict__ hD,
                                                      const int* __restrict__ batchP,
                                                      const int* __restrict__ batchD,
                                                      float* __restrict__ meanP,
                                                      float* __restrict__ meanD) {
    int t = threadIdx.x;
    if (t >= 240) return;
    int side = blockIdx.y;
    const float* h = side ? hD : hP;
    const int* batch = side ? batchD : batchP;
    float* meanRaw = side ? meanD : meanP;
    int q = t % 24, sub = t / 24;          // 10 node subgroups
    int base = blockIdx.x * 80;
    float4 acc = {0.f, 0.f, 0.f, 0.f};
    int cur = -1;
    for (int j = 0; j < 8; ++j) {
        int i = base + sub + j * 10;       // monotone in j
        if (i >= NN) continue;
        int g = batch[i];
        if (g != cur) {
            if (cur >= 0) {
                float* o = meanRaw + cur * HH + q * 4;
                atomicAdd(o + 0, acc.x); atomicAdd(o + 1, acc.y);
                atomicAdd(o + 2, acc.z); atomicAdd(o + 3, acc.w);
            }
            cur = g; acc.x = acc.y = acc.z = acc.w = 0.f;
        }
        float4 v = reinterpret_cast<const float4*>(h)[(size_t)i * 24 + q];
        acc.x += v.x; acc.y += v.y; acc.z += v.z; acc.w += v.w;
    }
    if (cur >= 0) {
        float* o = meanRaw + cur * HH + q * 4;
        atomicAdd(o + 0, acc.x); atomicAdd(o + 1, acc.y);
        atomicAdd(o + 2, acc.z); atomicAdd(o + 3, acc.w);
    }
}

// ---------------------------------------------------------------- final MLP (+ pooled normalization)
__global__ __launch_bounds__(128) void final_mlp(const float* __restrict__ meanP,
                                                 const float* __restrict__ meanD,
                                                 const float* __restrict__ attP,
                                                 const float* __restrict__ attD,
                                                 const float* __restrict__ den2,
                                                 const int* __restrict__ start2,
                                                 const float* __restrict__ lW0,
                                                 const float* __restrict__ lb0,
                                                 const float* __restrict__ lW1,
                                                 const float* __restrict__ lb1,
                                                 float* __restrict__ out) {
    __shared__ float in[2 * HH + 2 * FIN];   // 320
    __shared__ float red[2];
    int g = blockIdx.x, t = threadIdx.x;
    const int* startP = start2;
    const int* startD = start2 + (NG + 1);
    float cP = fmaxf((float)(startP[g + 1] - startP[g]), 1.0f);
    float cD = fmaxf((float)(startD[g + 1] - startD[g]), 1.0f);
    float dP = den2[g], dD = den2[NG + g];
    for (int idx = t; idx < 320; idx += 128) {
        float v;
        if (idx < 96)       v = meanP[g * HH + idx] / cP;
        else if (idx < 192) v = meanD[g * HH + idx - 96] / cD;
        else if (idx < 256) v = (dP > 0.f) ? attP[g * FIN + idx - 192] / dP : 0.0f;
        else                v = (dD > 0.f) ? attD[g * FIN + idx - 256] / dD : 0.0f;
        in[idx] = v;
    }
    __syncthreads();
    float hidv = 0.0f;
    if (t < HH) {
        float acc = lb0[t];
        for (int k = 0; k < 320; ++k) acc += in[k] * lW0[k * HH + t];
        hidv = fmaxf(acc, 0.0f) * lW1[t];
    }
    float v = wave_sum(hidv);
    if ((t & 63) == 0) red[t >> 6] = v;
    __syncthreads();
    if (t == 0) out[g] = red[0] + red[1] + lb1[0];
}

// ---------------------------------------------------------------- launch
extern "C" void kernel_launch(void* const* d_in, const int* in_sizes, int n_in,
                              void* d_out, int out_size, void* d_ws, size_t ws_size,
                              hipStream_t stream) {
    const float* x_p = (const float*)d_in[0];
    const float* x_d = (const float*)d_in[1];
    const int* ei_p = (const int*)d_in[4];
    const int* ei_d = (const int*)d_in[5];
    const int* batch_p = (const int*)d_in[6];
    const int* batch_d = (const int*)d_in[7];
    const float* Wp0 = (const float*)d_in[8];  const float* bp0 = (const float*)d_in[9];
    const float* Wp1 = (const float*)d_in[10]; const float* bp1 = (const float*)d_in[11];
    const float* Wp2 = (const float*)d_in[12]; const float* bp2 = (const float*)d_in[13];
    const float* Wd0 = (const float*)d_in[14]; const float* bd0 = (const float*)d_in[15];
    const float* Wd1 = (const float*)d_in[16]; const float* bd1 = (const float*)d_in[17];
    const float* Wd2 = (const float*)d_in[18]; const float* bd2 = (const float*)d_in[19];
    const float* gW1 = (const float*)d_in[20]; const float* gb1 = (const float*)d_in[21];
    const float* gW2 = (const float*)d_in[22]; const float* gb2 = (const float*)d_in[23];
    const float* lW0 = (const float*)d_in[24]; const float* lb0 = (const float*)d_in[25];
    const float* lW1 = (const float*)d_in[26]; const float* lb1 = (const float*)d_in[27];

    const int* src_p = ei_p;        const int* dst_p = ei_p + NE;
    const int* src_d = ei_d;        const int* dst_d = ei_d + NE;

    // -------- workspace carve-up
    char* ws = (char*)d_ws;
    size_t off = 0;
    auto alloc = [&](size_t bytes) -> void* {
        void* p = ws + off;
        off = (off + bytes + 255) & ~(size_t)255;
        return p;
    };
    float* agg_p = (float*)alloc((size_t)NN * HH * 4);        // fp32 layer io
    float* agg_d = (float*)alloc((size_t)NN * HH * 4);
    ushort4* xw_p = (ushort4*)alloc((size_t)NN * HH * 2);     // bf16 gemm out
    ushort4* xw_d = (ushort4*)alloc((size_t)NN * HH * 2);
    float* dinv2 = (float*)alloc((size_t)2 * NN * 4);
    int* rowptr2 = (int*)alloc((size_t)2 * (NN + 1) * 4);
    int* eSrc_p = (int*)alloc((size_t)NE * 4);
    int* eSrc_d = (int*)alloc((size_t)NE * 4);
    float* gate2 = (float*)alloc((size_t)2 * NN * 4);
    float* wgt2 = (float*)alloc((size_t)2 * NN * 4);
    int* start2 = (int*)alloc((size_t)2 * (NG + 1) * 4);
    float* den2 = (float*)alloc((size_t)2 * NG * 4);
    int* cntA = (int*)alloc((size_t)2 * BA * NCB * 4);        // fully written by permuteA
    int* bucketBase = (int*)alloc((size_t)2 * (NCB + 1) * 4);
    float* pooled = (float*)alloc((size_t)NG * (2 * HH + 2 * FIN) * 4);
    float* meanP = pooled;
    float* meanD = meanP + (size_t)NG * HH;
    float* attP  = meanD + (size_t)NG * HH;
    float* attD  = attP + (size_t)NG * FIN;
    // tmp edge buckets alias agg_p/agg_d (disjoint lifetime: done before gather L0)
    unsigned int* tmp_p = (unsigned int*)agg_p;               // 12.6 MB < 19.2 MB
    unsigned int* tmp_d = (unsigned int*)agg_d;
    (void)ws_size; (void)n_in; (void)in_sizes; (void)out_size;

    const int BNV = (NN * 24 + 255) / 256;
    const dim3 G2N(NB, 2), G2V(BNV, 2);
    const dim3 GEMM_GRID(NB, 4, 2);
    const dim3 GATE_GRID((NN + 63) / 64, 2);
    const dim3 GAB(NG, 2);
    const dim3 GATT((NN + 63) / 64, 2);
    const dim3 GMEAN((NN + 79) / 80, 2);

    // -------- zero pooled accumulators only
    hipMemsetAsync(pooled, 0, (size_t)NG * (2 * HH + 2 * FIN) * 4, stream);

    // -------- CSR build (LDS counting sort) + offsets + gate + att pooling
    permuteA<<<dim3(BA, 2), 256, 0, stream>>>(src_p, dst_p, src_d, dst_d, tmp_p, tmp_d, cntA);
    bucket_scan<<<2, 256, 0, stream>>>(cntA, bucketBase);
    permuteB<<<dim3(NCB, 2), 256, 0, stream>>>(tmp_p, tmp_d, cntA, bucketBase,
                                               rowptr2, dinv2, eSrc_p, eSrc_d);
    start_both<<<G2N, 256, 0, stream>>>(batch_p, batch_d, start2);
    gate_both<<<GATE_GRID, 256, 0, stream>>>(x_p, x_d, gW1, gb1, gW2, gb2, gate2);
    pool_ab_wgt<<<GAB, 256, 0, stream>>>(gate2, start2, den2, wgt2);
    pool_att_both<<<GATT, 256, 0, stream>>>(wgt2, x_p, x_d, batch_p, batch_d, attP, attD);

    // -------- 3 GCN layers, both sides per dispatch
    gemm_both<FIN, false><<<GEMM_GRID, 256, 0, stream>>>(x_p, x_d, Wp0, Wd0, xw_p, xw_d);
    gather_both<<<G2V, 256, 0, stream>>>(xw_p, xw_d, dinv2, bp0, bd0, rowptr2, eSrc_p, eSrc_d, agg_p, agg_d);
    gemm_both<HH, true><<<GEMM_GRID, 256, 0, stream>>>(agg_p, agg_d, Wp1, Wd1, xw_p, xw_d);
    gather_both<<<G2V, 256, 0, stream>>>(xw_p, xw_d, dinv2, bp1, bd1, rowptr2, eSrc_p, eSrc_d, agg_p, agg_d);
    gemm_both<HH, true><<<GEMM_GRID, 256, 0, stream>>>(agg_p, agg_d, Wp2, Wd2, xw_p, xw_d);
    gather_both<<<G2V, 256, 0, stream>>>(xw_p, xw_d, dinv2, bp2, bd2, rowptr2, eSrc_p, eSrc_d, agg_p, agg_d);
    pool_mean_both<<<GMEAN, 256, 0, stream>>>(agg_p, agg_d, batch_p, batch_d, meanP, meanD);

    // -------- final MLP
    final_mlp<<<NG, 128, 0, stream>>>(meanP, meanD, attP, attD, den2, start2,
                                      lW0, lb0, lW1, lb1, (float*)d_out);
}